// Round 3
// baseline (109.221 us; speedup 1.0000x reference)
//
#include <hip/hip_runtime.h>

// QME loss: mean over B of 2*(|p1*t1| + |p2*t2| + |p3*t3|)
// Single fused kernel: grid-stride streaming reduce -> per-block fixed-point
// u64 atomic (deterministic, order-independent) -> last block finalizes.
// ws layout: [0..7] u64 accumulator, [8..11] u32 done-counter (memset to 0
// per call on the stream).

__global__ void qme_fused(const float4* __restrict__ pred,
                          const float4* __restrict__ tru,
                          unsigned long long* __restrict__ ws,
                          float* __restrict__ out, int n, float scale) {
    int tid = blockIdx.x * blockDim.x + threadIdx.x;
    int S = gridDim.x * blockDim.x;
    float acc = 0.0f;
    for (int i = tid; i < n; i += S) {
        float4 p = pred[i];
        float4 t = tru[i];
        acc += fabsf(p.y * t.y) + fabsf(p.z * t.z) + fabsf(p.w * t.w);
    }
    // wave-64 shuffle reduce
    #pragma unroll
    for (int off = 32; off > 0; off >>= 1)
        acc += __shfl_down(acc, off, 64);
    __shared__ float lds[4];  // 256 threads = 4 waves
    int wave = threadIdx.x >> 6;
    if ((threadIdx.x & 63) == 0) lds[wave] = acc;
    __syncthreads();

    if (threadIdx.x == 0) {
        float bsum = lds[0] + lds[1] + lds[2] + lds[3];
        // fixed-point 2^20: deterministic integer accumulation
        unsigned long long fx =
            (unsigned long long)((double)bsum * 1048576.0 + 0.5);
        atomicAdd(&ws[0], fx);
        __threadfence();
        unsigned int prev = atomicAdd((unsigned int*)&ws[1], 1u);
        if (prev == gridDim.x - 1) {
            unsigned long long total = atomicAdd(&ws[0], 0ULL);  // atomic read
            out[0] = (float)((double)total * (1.0 / 1048576.0) * (double)scale);
        }
    }
}

extern "C" void kernel_launch(void* const* d_in, const int* in_sizes, int n_in,
                              void* d_out, int out_size, void* d_ws, size_t ws_size,
                              hipStream_t stream) {
    const float4* pred = (const float4*)d_in[0];
    const float4* tru  = (const float4*)d_in[1];
    float* out = (float*)d_out;
    unsigned long long* ws = (unsigned long long*)d_ws;

    int n = in_sizes[0] / 4;          // number of quaternions (8388608)
    const int threads = 256;
    const int blocks = 2048;          // 256 CUs x 8 blocks/CU, fully co-resident

    hipMemsetAsync(d_ws, 0, 16, stream);   // zero accumulator + counter
    qme_fused<<<blocks, threads, 0, stream>>>(pred, tru, ws, out, n,
                                              2.0f / (float)n);
}

// Round 4
// 51.090 us; speedup vs baseline: 2.1378x; 2.1378x over previous
//
#include <hip/hip_runtime.h>

// QME loss: mean over B of 2*(|p1*t1| + |p2*t2| + |p3*t3|)
// Two-kernel streaming reduction (R1 structure — fastest measured).
// R3 post-mortem: single-kernel last-block-done with contended device-scope
// atomics from 2048 blocks costs ~80 us of serialized tail across 8 XCDs.
// The graph-replay gap between two kernel nodes is ~2-4 us -> keep the split.

__global__ void qme_partial(const float4* __restrict__ pred,
                            const float4* __restrict__ tru,
                            float* __restrict__ partial, int n) {
    int tid = blockIdx.x * blockDim.x + threadIdx.x;
    int S = gridDim.x * blockDim.x;
    float acc = 0.0f;
    for (int i = tid; i < n; i += S) {
        float4 p = pred[i];
        float4 t = tru[i];
        acc += fabsf(p.y * t.y) + fabsf(p.z * t.z) + fabsf(p.w * t.w);
    }
    // wave-64 shuffle reduce
    #pragma unroll
    for (int off = 32; off > 0; off >>= 1)
        acc += __shfl_down(acc, off, 64);
    __shared__ float lds[4];  // 256 threads = 4 waves
    int wave = threadIdx.x >> 6;
    if ((threadIdx.x & 63) == 0) lds[wave] = acc;
    __syncthreads();
    if (threadIdx.x == 0)
        partial[blockIdx.x] = lds[0] + lds[1] + lds[2] + lds[3];
}

// 128 threads (2 waves): each thread reads 16 coalesced partials.
__global__ void qme_final(const float* __restrict__ partial, int nblocks,
                          float* __restrict__ out, float scale) {
    float acc = 0.0f;
    for (int i = threadIdx.x; i < nblocks; i += 128)
        acc += partial[i];
    #pragma unroll
    for (int off = 32; off > 0; off >>= 1)
        acc += __shfl_down(acc, off, 64);
    __shared__ float lds[2];
    if ((threadIdx.x & 63) == 0) lds[threadIdx.x >> 6] = acc;
    __syncthreads();
    if (threadIdx.x == 0)
        out[0] = (lds[0] + lds[1]) * scale;
}

extern "C" void kernel_launch(void* const* d_in, const int* in_sizes, int n_in,
                              void* d_out, int out_size, void* d_ws, size_t ws_size,
                              hipStream_t stream) {
    const float4* pred = (const float4*)d_in[0];
    const float4* tru  = (const float4*)d_in[1];
    float* out = (float*)d_out;
    float* partial = (float*)d_ws;

    int n = in_sizes[0] / 4;          // number of quaternions (8388608)
    const int threads = 256;
    const int blocks = 2048;          // 256 CUs x 8 blocks/CU, fully co-resident

    qme_partial<<<blocks, threads, 0, stream>>>(pred, tru, partial, n);
    qme_final<<<1, 128, 0, stream>>>(partial, blocks, out, 2.0f / (float)n);
}

// Round 5
// 47.568 us; speedup vs baseline: 2.2961x; 1.0740x over previous
//
#include <hip/hip_runtime.h>

// QME loss: mean over B of 2*(|p1*t1| + |p2*t2| + |p3*t3|)
// Two-kernel streaming reduction. Measured floor analysis:
//   traffic 268.4 MB irreducible (x-component shares cache lines)
//   -> 42.6 us at 6.3 TB/s copy ceiling; partial kernel ~45.5 us (94%).
// R2: deeper MLP neutral (not latency-bound). R3: fused contended atomics
// +80 us tail (2048 same-line RMWs across 8 XCDs) — never again.
// Final kernel: 256 threads, float4 loads over the 2048 partials.

__global__ void qme_partial(const float4* __restrict__ pred,
                            const float4* __restrict__ tru,
                            float* __restrict__ partial, int n) {
    int tid = blockIdx.x * blockDim.x + threadIdx.x;
    int S = gridDim.x * blockDim.x;
    float acc = 0.0f;
    for (int i = tid; i < n; i += S) {
        float4 p = pred[i];
        float4 t = tru[i];
        acc += fabsf(p.y * t.y) + fabsf(p.z * t.z) + fabsf(p.w * t.w);
    }
    // wave-64 shuffle reduce
    #pragma unroll
    for (int off = 32; off > 0; off >>= 1)
        acc += __shfl_down(acc, off, 64);
    __shared__ float lds[4];  // 256 threads = 4 waves
    int wave = threadIdx.x >> 6;
    if ((threadIdx.x & 63) == 0) lds[wave] = acc;
    __syncthreads();
    if (threadIdx.x == 0)
        partial[blockIdx.x] = lds[0] + lds[1] + lds[2] + lds[3];
}

// 2048 partials = 512 float4; 256 threads read 2 float4 each (coalesced).
__global__ void qme_final(const float4* __restrict__ partial4,
                          float* __restrict__ out, float scale) {
    float4 a = partial4[threadIdx.x];
    float4 b = partial4[threadIdx.x + 256];
    float acc = (a.x + a.y + a.z + a.w) + (b.x + b.y + b.z + b.w);
    #pragma unroll
    for (int off = 32; off > 0; off >>= 1)
        acc += __shfl_down(acc, off, 64);
    __shared__ float lds[4];
    if ((threadIdx.x & 63) == 0) lds[threadIdx.x >> 6] = acc;
    __syncthreads();
    if (threadIdx.x == 0)
        out[0] = (lds[0] + lds[1] + lds[2] + lds[3]) * scale;
}

extern "C" void kernel_launch(void* const* d_in, const int* in_sizes, int n_in,
                              void* d_out, int out_size, void* d_ws, size_t ws_size,
                              hipStream_t stream) {
    const float4* pred = (const float4*)d_in[0];
    const float4* tru  = (const float4*)d_in[1];
    float* out = (float*)d_out;
    float* partial = (float*)d_ws;

    int n = in_sizes[0] / 4;          // number of quaternions (8388608)
    const int threads = 256;
    const int blocks = 2048;          // 256 CUs x 8 blocks/CU, fully co-resident

    qme_partial<<<blocks, threads, 0, stream>>>(pred, tru, partial, n);
    qme_final<<<1, 256, 0, stream>>>((const float4*)partial, out,
                                     2.0f / (float)n);
}